// Round 12
// baseline (185.266 us; speedup 1.0000x reference)
//
#include <hip/hip_runtime.h>

#define HH 128
#define WW 128
#define BB 4
#define CC 64
#define CHN 21
#define CHP 24           // padded channel count (channel-last, 48 B/px)
#define NPIX (HH*WW)     // 16384
#define NTAP 24
#define PAD 4
#define PW 136
#define PH 136
#define PPLANE (PW*PH)   // 18496
#define AGR 4            // affinity channel groups per block
#define ACH (CC/AGR)     // 16 channels per thread
#define TS 32            // prop2 output tile side
#define MS 40            // intermediate tile side (TS + 2*PAD)

typedef _Float16 h8 __attribute__((ext_vector_type(8)));

// 7 distinct tap displacements; tap k uses (DYS7[TIY[k]], DYS7[TIX[k]]).
// Order matches reference: dil 1 taps 0-7, dil 2 taps 8-15, dil 4 taps 16-23.
constexpr int DYS7[7] = {-4, -2, -1, 0, 1, 2, 4};
constexpr int TIY[NTAP] = {2,2,2,3,3,4,4,4, 1,1,1,3,3,5,5,5, 0,0,0,3,3,6,6,6};
constexpr int TIX[NTAP] = {2,3,4,2,4,2,3,4, 1,3,5,1,5,1,3,5, 0,3,6,0,6,0,3,6};

__device__ __forceinline__ int clampi(int v, int lo, int hi) {
    return v < lo ? lo : (v > hi ? hi : v);
}

// ---- pad+transpose mask: [B,21,128,128] f32 -> [B,136*136,24] fp16 ---------
__global__ __launch_bounds__(256) void pad_mask_kernel(
    const float* __restrict__ mask, _Float16* __restrict__ pm) {
    int t = blockIdx.x * blockDim.x + threadIdx.x;
    const int total = BB * PPLANE;
    if (t >= total) return;
    int pp = t % PPLANE;
    int b = t / PPLANE;
    int ph = pp / PW, pw = pp % PW;
    int sh = clampi(ph - PAD, 0, HH - 1);
    int sw = clampi(pw - PAD, 0, WW - 1);
    const float* sp = mask + (size_t)b * CHN * NPIX + (size_t)sh * WW + sw;
    _Float16* dp = pm + ((size_t)b * PPLANE + pp) * CHP;
    h8 o0, o1, o2;
    #pragma unroll
    for (int c = 0; c < 8; ++c)  o0[c] = (_Float16)sp[(size_t)c * NPIX];
    #pragma unroll
    for (int c = 0; c < 8; ++c)  o1[c] = (_Float16)sp[(size_t)(c + 8) * NPIX];
    #pragma unroll
    for (int c = 0; c < 5; ++c)  o2[c] = (_Float16)sp[(size_t)(c + 16) * NPIX];
    o2[5] = (_Float16)0.f; o2[6] = (_Float16)0.f; o2[7] = (_Float16)0.f;
    *((h8*)(dp + 0))  = o0;
    *((h8*)(dp + 8))  = o1;
    *((h8*)(dp + 16)) = o2;
}

// ---- fused affinity: reads f32 feats directly (clamped offsets) ------------
// aff layout: [b][3][NPIX] h8 quads (8 taps each, fp16).
__global__ __launch_bounds__(256) void affinity_kernel(
    const float* __restrict__ feats, h8* __restrict__ aff) {
    __shared__ float red[AGR][64][NTAP + 1];

    int t = threadIdx.x;
    int g = t >> 6;                  // 0..3 channel group
    int px = t & 63;
    int blk = blockIdx.x;            // 0..1023
    int w = (blk & 1) * 64 + px;
    int h = (blk >> 1) & 127;
    int b = blk >> 8;

    int ro[7], co[7];
    #pragma unroll
    for (int i = 0; i < 7; ++i) {
        ro[i] = clampi(h + DYS7[i], 0, HH - 1) * WW;
        co[i] = clampi(w + DYS7[i], 0, WW - 1);
    }

    float acc[NTAP];
    #pragma unroll
    for (int k = 0; k < NTAP; ++k) acc[k] = 0.f;

    const float* fc = feats + (size_t)(b * CC + g * ACH) * NPIX;
    for (int c = 0; c < ACH; ++c, fc += NPIX) {
        float q = fc[ro[3] + co[3]];
        float sum = 3.f * q, ss = 3.f * q * q;   // center window x3 dilations
        float v[NTAP];
        #pragma unroll
        for (int k = 0; k < NTAP; ++k) {
            float x = fc[ro[TIY[k]] + co[TIX[k]]];
            v[k] = x;
            sum += x;
            ss = fmaf(x, x, ss);
        }
        float var = (ss - sum * sum * (1.f/27.f)) * (1.f/26.f);
        float inv = 1.f / (1e-8f + 0.1f * sqrtf(fmaxf(var, 0.f)));
        #pragma unroll
        for (int k = 0; k < NTAP; ++k)
            acc[k] = fmaf(fabsf(v[k] - q), inv, acc[k]);   // positive; negate in softmax
    }

    #pragma unroll
    for (int k = 0; k < NTAP; ++k) red[g][px][k] = acc[k];
    __syncthreads();

    if (t < 64) {
        float s[NTAP];
        #pragma unroll
        for (int k = 0; k < NTAP; ++k)
            s[k] = (red[0][t][k] + red[1][t][k]) + (red[2][t][k] + red[3][t][k]);
        float mn = s[0];
        #pragma unroll
        for (int k = 1; k < NTAP; ++k) mn = fminf(mn, s[k]);
        float e[NTAP];
        float tot = 0.f;
        #pragma unroll
        for (int k = 0; k < NTAP; ++k) {
            e[k] = __expf((mn - s[k]) * (1.f/CC));
            tot += e[k];
        }
        float ivt = 1.f / tot;
        int pix = h * WW + (blk & 1) * 64 + t;
        #pragma unroll
        for (int j = 0; j < 3; ++j) {
            h8 q;
            #pragma unroll
            for (int i = 0; i < 8; ++i) q[i] = (_Float16)(e[8*j + i] * ivt);
            aff[((size_t)b * 3 + j) * NPIX + pix] = q;
        }
    }
}

// ---- prop2: TWO fused iterations per dispatch ------------------------------
// Phase 1: 40x40 intermediate (tile + halo 4, clamped coords) -> LDS.
// Phase 2: 32x32 output tile from LDS.
// src/dst: [b][PPLANE][24] fp16 channel-last. aff: [b][3][NPIX] h8.
__global__ __launch_bounds__(256) void prop2_kernel(
    const _Float16* __restrict__ src, const h8* __restrict__ aff,
    _Float16* __restrict__ dstp, float* __restrict__ dstf, int final_iter) {
    __shared__ __align__(16) _Float16 mid[MS * MS * 8];   // 25.6 KB

    int tid = threadIdx.x;
    int tx = (blockIdx.x & 3) * TS;
    int ty = (blockIdx.x >> 2) * TS;
    int cg = blockIdx.y;             // 0..2 (channels cg*8 .. cg*8+7)
    int b  = blockIdx.z;

    // ---- phase 1: intermediate iteration into LDS
    for (int p = tid; p < MS * MS; p += 256) {
        int y = p / MS, x = p - y * MS;
        int gh = clampi(ty + y - PAD, 0, HH - 1);
        int gw = clampi(tx + x - PAD, 0, WW - 1);
        int pix = gh * WW + gw;

        float A[NTAP];
        #pragma unroll
        for (int j = 0; j < 3; ++j) {
            h8 q = aff[((size_t)b * 3 + j) * NPIX + pix];
            #pragma unroll
            for (int i = 0; i < 8; ++i) A[8*j + i] = (float)q[i];
        }

        const _Float16* base = src
            + ((size_t)b * PPLANE + (gh + PAD) * PW + (gw + PAD)) * CHP + cg * 8;
        float acc[8];
        #pragma unroll
        for (int i = 0; i < 8; ++i) acc[i] = 0.f;
        #pragma unroll
        for (int k = 0; k < NTAP; ++k) {
            h8 m = *((const h8*)(base + (DYS7[TIY[k]] * PW + DYS7[TIX[k]]) * CHP));
            #pragma unroll
            for (int i = 0; i < 8; ++i) acc[i] = fmaf((float)m[i], A[k], acc[i]);
        }
        h8 o;
        #pragma unroll
        for (int i = 0; i < 8; ++i) o[i] = (_Float16)acc[i];
        *((h8*)(mid + (size_t)p * 8)) = o;
    }
    __syncthreads();

    // ---- phase 2: final iteration of the pair from LDS
    for (int p = tid; p < TS * TS; p += 256) {
        int y2 = p >> 5, x2 = p & 31;
        int gh = ty + y2, gw = tx + x2;
        int pix = gh * WW + gw;

        float A[NTAP];
        #pragma unroll
        for (int j = 0; j < 3; ++j) {
            h8 q = aff[((size_t)b * 3 + j) * NPIX + pix];
            #pragma unroll
            for (int i = 0; i < 8; ++i) A[8*j + i] = (float)q[i];
        }

        const _Float16* mbase = mid + ((size_t)(y2 + PAD) * MS + (x2 + PAD)) * 8;
        float acc[8];
        #pragma unroll
        for (int i = 0; i < 8; ++i) acc[i] = 0.f;
        #pragma unroll
        for (int k = 0; k < NTAP; ++k) {
            h8 m = *((const h8*)(mbase + (DYS7[TIY[k]] * MS + DYS7[TIX[k]]) * 8));
            #pragma unroll
            for (int i = 0; i < 8; ++i) acc[i] = fmaf((float)m[i], A[k], acc[i]);
        }

        if (final_iter) {
            float* ob = dstf + (size_t)b * CHN * NPIX + pix;
            #pragma unroll
            for (int i = 0; i < 8; ++i) {
                int ch = cg * 8 + i;
                if (ch < CHN) ob[(size_t)ch * NPIX] = acc[i];
            }
        } else {
            h8 o;
            #pragma unroll
            for (int i = 0; i < 8; ++i) o[i] = (_Float16)acc[i];
            _Float16* pd = dstp + (size_t)b * PPLANE * CHP + cg * 8;
            int pp = (gh + PAD) * PW + (gw + PAD);
            int x0 = (gw == 0) ? -PAD : 0, x1 = (gw == WW - 1) ? PAD : 0;
            int y0 = (gh == 0) ? -PAD : 0, y1 = (gh == HH - 1) ? PAD : 0;
            for (int dy = y0; dy <= y1; ++dy)
                for (int dx = x0; dx <= x1; ++dx)
                    *((h8*)(pd + (size_t)(pp + dy * PW + dx) * CHP)) = o;
        }
    }
}

extern "C" void kernel_launch(void* const* d_in, const int* in_sizes, int n_in,
                              void* d_out, int out_size, void* d_ws, size_t ws_size,
                              hipStream_t stream) {
    const float* feats = (const float*)d_in[0];
    const float* mask  = (const float*)d_in[1];
    float* out = (float*)d_out;

    const size_t affQ = (size_t)BB * 3 * NPIX;          // h8 (16 B each)
    const size_t pmE  = (size_t)BB * PPLANE * CHP;      // halfs

    h8*       aff = (h8*)d_ws;
    _Float16* pm0 = (_Float16*)((char*)aff + affQ * sizeof(h8));
    _Float16* pm1 = pm0 + pmE;

    affinity_kernel<<<dim3(BB * NPIX / 64), dim3(256), 0, stream>>>(feats, aff);
    {
        int total = BB * PPLANE;
        pad_mask_kernel<<<dim3((total + 255) / 256), dim3(256), 0, stream>>>(mask, pm0);
    }

    // 5 fused dispatches = 10 iterations; ping-pong pm0/pm1, last writes f32 out
    prop2_kernel<<<dim3(16, 3, BB), dim3(256), 0, stream>>>(pm0, aff, pm1, nullptr, 0);
    prop2_kernel<<<dim3(16, 3, BB), dim3(256), 0, stream>>>(pm1, aff, pm0, nullptr, 0);
    prop2_kernel<<<dim3(16, 3, BB), dim3(256), 0, stream>>>(pm0, aff, pm1, nullptr, 0);
    prop2_kernel<<<dim3(16, 3, BB), dim3(256), 0, stream>>>(pm1, aff, pm0, nullptr, 0);
    prop2_kernel<<<dim3(16, 3, BB), dim3(256), 0, stream>>>(pm0, aff, nullptr, out, 1);
}

// Round 13
// 111.560 us; speedup vs baseline: 1.6607x; 1.6607x over previous
//
#include <hip/hip_runtime.h>

#define HH 128
#define WW 128
#define BB 4
#define CC 64
#define CHN 21
#define CHP 24           // padded channel count (channel-last, 48 B/px)
#define NPIX (HH*WW)     // 16384
#define NTAP 24
#define PAD 4
#define PW 136
#define PH 136
#define PPLANE (PW*PH)   // 18496
#define PWQ (PW/4)       // 34
#define AGR 4            // affinity channel groups per block
#define ACH (CC/AGR)     // 16 channels per thread
#define TS 16            // prop2 output tile side
#define MS 24            // intermediate tile side (TS + 2*PAD)

typedef _Float16 h4 __attribute__((ext_vector_type(4)));
typedef _Float16 h8 __attribute__((ext_vector_type(8)));

// Tap offsets in the padded plane (row stride PW, pixel units), reference order.
constexpr int TAPOFF[NTAP] = {
    -PW-1, -PW, -PW+1, -1, 1, PW-1, PW, PW+1,
    -2*PW-2, -2*PW, -2*PW+2, -2, 2, 2*PW-2, 2*PW, 2*PW+2,
    -4*PW-4, -4*PW, -4*PW+4, -4, 4, 4*PW-4, 4*PW, 4*PW+4
};
// Same taps with row stride MS (for the LDS mid tile).
constexpr int MIDOFF[NTAP] = {
    -MS-1, -MS, -MS+1, -1, 1, MS-1, MS, MS+1,
    -2*MS-2, -2*MS, -2*MS+2, -2, 2, 2*MS-2, 2*MS, 2*MS+2,
    -4*MS-4, -4*MS, -4*MS+4, -4, 4, 4*MS-4, 4*MS, 4*MS+4
};

__device__ __forceinline__ int clampi(int v, int lo, int hi) {
    return v < lo ? lo : (v > hi ? hi : v);
}

// ---- pad feats: edge-replicate [B,C,128,128] f32 -> [B,C,136,136] fp16 -----
__global__ __launch_bounds__(256) void pad_feats_kernel(
    const float* __restrict__ feats, _Float16* __restrict__ pfeats) {
    int t = blockIdx.x * blockDim.x + threadIdx.x;
    const int total = BB * CC * PH * PWQ;
    if (t >= total) return;
    int q = t % PWQ;
    int rest = t / PWQ;
    int ph = rest % PH;
    int pl = rest / PH;
    const float* sp = feats + (size_t)pl * NPIX + (size_t)clampi(ph - PAD, 0, HH - 1) * WW;
    h4 v;
    v[0] = (_Float16)sp[clampi(q * 4 + 0 - PAD, 0, WW - 1)];
    v[1] = (_Float16)sp[clampi(q * 4 + 1 - PAD, 0, WW - 1)];
    v[2] = (_Float16)sp[clampi(q * 4 + 2 - PAD, 0, WW - 1)];
    v[3] = (_Float16)sp[clampi(q * 4 + 3 - PAD, 0, WW - 1)];
    *((h4*)(pfeats + (size_t)pl * PPLANE + (size_t)ph * PW + q * 4)) = v;
}

// ---- pad+transpose mask: [B,21,128,128] f32 -> [B,136*136,24] fp16 ---------
__global__ __launch_bounds__(256) void pad_mask_kernel(
    const float* __restrict__ mask, _Float16* __restrict__ pm) {
    int t = blockIdx.x * blockDim.x + threadIdx.x;
    const int total = BB * PPLANE;
    if (t >= total) return;
    int pp = t % PPLANE;
    int b = t / PPLANE;
    int ph = pp / PW, pw = pp % PW;
    int sh = clampi(ph - PAD, 0, HH - 1);
    int sw = clampi(pw - PAD, 0, WW - 1);
    const float* sp = mask + (size_t)b * CHN * NPIX + (size_t)sh * WW + sw;
    _Float16* dp = pm + ((size_t)b * PPLANE + pp) * CHP;
    h8 o0, o1, o2;
    #pragma unroll
    for (int c = 0; c < 8; ++c)  o0[c] = (_Float16)sp[(size_t)c * NPIX];
    #pragma unroll
    for (int c = 0; c < 8; ++c)  o1[c] = (_Float16)sp[(size_t)(c + 8) * NPIX];
    #pragma unroll
    for (int c = 0; c < 5; ++c)  o2[c] = (_Float16)sp[(size_t)(c + 16) * NPIX];
    o2[5] = (_Float16)0.f; o2[6] = (_Float16)0.f; o2[7] = (_Float16)0.f;
    *((h8*)(dp + 0))  = o0;
    *((h8*)(dp + 8))  = o1;
    *((h8*)(dp + 16)) = o2;
}

// ---- fused affinity (R11 version): fp16 padded feats, h8 aff out -----------
// aff layout: [b][3][NPIX] h8 quads (8 taps each, fp16).
__global__ __launch_bounds__(256) void affinity_kernel(
    const _Float16* __restrict__ pfeats, h8* __restrict__ aff) {
    __shared__ float red[AGR][64][NTAP + 1];

    int t = threadIdx.x;
    int g = t >> 6;
    int px = t & 63;
    int blk = blockIdx.x;
    int w = (blk & 1) * 64 + px;
    int h = (blk >> 1) & 127;
    int b = blk >> 8;

    const _Float16* base0 = pfeats + (size_t)(b * CC + g * ACH) * PPLANE
                          + (size_t)(h + PAD) * PW + (w + PAD);

    float acc[NTAP];
    #pragma unroll
    for (int k = 0; k < NTAP; ++k) acc[k] = 0.f;

    for (int c = 0; c < ACH; ++c) {
        const _Float16* base = base0 + (size_t)c * PPLANE;
        float q = (float)base[0];
        float sum = 3.f * q, ss = 3.f * q * q;
        float v[NTAP];
        #pragma unroll
        for (int k = 0; k < NTAP; ++k) {
            float x = (float)base[TAPOFF[k]];
            v[k] = x;
            sum += x;
            ss = fmaf(x, x, ss);
        }
        float var = (ss - sum * sum * (1.f/27.f)) * (1.f/26.f);
        float inv = 1.f / (1e-8f + 0.1f * sqrtf(fmaxf(var, 0.f)));
        #pragma unroll
        for (int k = 0; k < NTAP; ++k)
            acc[k] = fmaf(fabsf(v[k] - q), inv, acc[k]);
    }

    #pragma unroll
    for (int k = 0; k < NTAP; ++k) red[g][px][k] = acc[k];
    __syncthreads();

    if (t < 64) {
        float s[NTAP];
        #pragma unroll
        for (int k = 0; k < NTAP; ++k)
            s[k] = (red[0][t][k] + red[1][t][k]) + (red[2][t][k] + red[3][t][k]);
        float mn = s[0];
        #pragma unroll
        for (int k = 1; k < NTAP; ++k) mn = fminf(mn, s[k]);
        float e[NTAP];
        float tot = 0.f;
        #pragma unroll
        for (int k = 0; k < NTAP; ++k) {
            e[k] = __expf((mn - s[k]) * (1.f/CC));
            tot += e[k];
        }
        float ivt = 1.f / tot;
        int pix = h * WW + (blk & 1) * 64 + t;
        #pragma unroll
        for (int j = 0; j < 3; ++j) {
            h8 q;
            #pragma unroll
            for (int i = 0; i < 8; ++i) q[i] = (_Float16)(e[8*j + i] * ivt);
            aff[((size_t)b * 3 + j) * NPIX + pix] = q;
        }
    }
}

// ---- prop2: TWO fused iterations, 16x16 tile, 768 blocks -------------------
// Phase 1: 24x24 intermediate (tile + halo 4, clamped coords) -> LDS.
// Phase 2: 16x16 output tile from LDS.
__global__ __launch_bounds__(256, 3) void prop2_kernel(
    const _Float16* __restrict__ src, const h8* __restrict__ aff,
    _Float16* __restrict__ dstp, float* __restrict__ dstf, int final_iter) {
    __shared__ __align__(16) _Float16 mid[MS * MS * 8];   // 9.2 KB

    int tid = threadIdx.x;
    int tx = (blockIdx.x & 7) * TS;
    int ty = (blockIdx.x >> 3) * TS;
    int cg = blockIdx.y;             // 0..2 (channels cg*8 .. cg*8+7)
    int b  = blockIdx.z;

    // ---- phase 1: intermediate iteration into LDS (2.25 px/thread)
    for (int p = tid; p < MS * MS; p += 256) {
        int y = p / MS, x = p - y * MS;
        int gh = clampi(ty + y - PAD, 0, HH - 1);
        int gw = clampi(tx + x - PAD, 0, WW - 1);
        int pix = gh * WW + gw;

        float A[NTAP];
        #pragma unroll
        for (int j = 0; j < 3; ++j) {
            h8 q = aff[((size_t)b * 3 + j) * NPIX + pix];
            #pragma unroll
            for (int i = 0; i < 8; ++i) A[8*j + i] = (float)q[i];
        }

        const _Float16* base = src
            + ((size_t)b * PPLANE + (gh + PAD) * PW + (gw + PAD)) * CHP + cg * 8;
        float acc[8];
        #pragma unroll
        for (int i = 0; i < 8; ++i) acc[i] = 0.f;
        #pragma unroll
        for (int k = 0; k < NTAP; ++k) {
            h8 m = *((const h8*)(base + (ptrdiff_t)TAPOFF[k] * CHP));
            #pragma unroll
            for (int i = 0; i < 8; ++i) acc[i] = fmaf((float)m[i], A[k], acc[i]);
        }
        h8 o;
        #pragma unroll
        for (int i = 0; i < 8; ++i) o[i] = (_Float16)acc[i];
        *((h8*)(mid + (size_t)p * 8)) = o;
    }
    __syncthreads();

    // ---- phase 2: final iteration of the pair from LDS (1 px/thread)
    {
        int p = tid;
        int y2 = p >> 4, x2 = p & 15;
        int gh = ty + y2, gw = tx + x2;
        int pix = gh * WW + gw;

        float A[NTAP];
        #pragma unroll
        for (int j = 0; j < 3; ++j) {
            h8 q = aff[((size_t)b * 3 + j) * NPIX + pix];
            #pragma unroll
            for (int i = 0; i < 8; ++i) A[8*j + i] = (float)q[i];
        }

        const _Float16* mbase = mid + ((size_t)(y2 + PAD) * MS + (x2 + PAD)) * 8;
        float acc[8];
        #pragma unroll
        for (int i = 0; i < 8; ++i) acc[i] = 0.f;
        #pragma unroll
        for (int k = 0; k < NTAP; ++k) {
            h8 m = *((const h8*)(mbase + (ptrdiff_t)MIDOFF[k] * 8));
            #pragma unroll
            for (int i = 0; i < 8; ++i) acc[i] = fmaf((float)m[i], A[k], acc[i]);
        }

        if (final_iter) {
            float* ob = dstf + (size_t)b * CHN * NPIX + pix;
            #pragma unroll
            for (int i = 0; i < 8; ++i) {
                int ch = cg * 8 + i;
                if (ch < CHN) ob[(size_t)ch * NPIX] = acc[i];
            }
        } else {
            h8 o;
            #pragma unroll
            for (int i = 0; i < 8; ++i) o[i] = (_Float16)acc[i];
            _Float16* pd = dstp + (size_t)b * PPLANE * CHP + cg * 8;
            int pp = (gh + PAD) * PW + (gw + PAD);
            int x0 = (gw == 0) ? -PAD : 0, x1 = (gw == WW - 1) ? PAD : 0;
            int y0 = (gh == 0) ? -PAD : 0, y1 = (gh == HH - 1) ? PAD : 0;
            for (int dy = y0; dy <= y1; ++dy)
                for (int dx = x0; dx <= x1; ++dx)
                    *((h8*)(pd + (size_t)(pp + dy * PW + dx) * CHP)) = o;
        }
    }
}

extern "C" void kernel_launch(void* const* d_in, const int* in_sizes, int n_in,
                              void* d_out, int out_size, void* d_ws, size_t ws_size,
                              hipStream_t stream) {
    const float* feats = (const float*)d_in[0];
    const float* mask  = (const float*)d_in[1];
    float* out = (float*)d_out;

    const size_t pfeatsE = (size_t)BB * CC * PPLANE;    // halfs
    const size_t affQ    = (size_t)BB * 3 * NPIX;       // h8 (16 B each)
    const size_t pmE     = (size_t)BB * PPLANE * CHP;   // halfs

    _Float16* pfeats = (_Float16*)d_ws;
    h8*       aff    = (h8*)(pfeats + pfeatsE);
    _Float16* pm0    = (_Float16*)((char*)aff + affQ * sizeof(h8));
    _Float16* pm1    = pm0 + pmE;

    {
        int total = BB * CC * PH * PWQ;
        pad_feats_kernel<<<dim3((total + 255) / 256), dim3(256), 0, stream>>>(feats, pfeats);
    }
    {
        int total = BB * PPLANE;
        pad_mask_kernel<<<dim3((total + 255) / 256), dim3(256), 0, stream>>>(mask, pm0);
    }
    affinity_kernel<<<dim3(BB * NPIX / 64), dim3(256), 0, stream>>>(pfeats, aff);

    // 5 fused dispatches = 10 iterations; ping-pong pm0/pm1, last writes f32 out
    dim3 g2(64, 3, BB);
    prop2_kernel<<<g2, dim3(256), 0, stream>>>(pm0, aff, pm1, nullptr, 0);
    prop2_kernel<<<g2, dim3(256), 0, stream>>>(pm1, aff, pm0, nullptr, 0);
    prop2_kernel<<<g2, dim3(256), 0, stream>>>(pm0, aff, pm1, nullptr, 0);
    prop2_kernel<<<g2, dim3(256), 0, stream>>>(pm1, aff, pm0, nullptr, 0);
    prop2_kernel<<<g2, dim3(256), 0, stream>>>(pm0, aff, nullptr, out, 1);
}

// Round 14
// 109.755 us; speedup vs baseline: 1.6880x; 1.0164x over previous
//
#include <hip/hip_runtime.h>

#define HH 128
#define WW 128
#define BB 4
#define CC 64
#define CHN 21
#define CHP 24           // padded channel count (channel-last, 48 B/px)
#define NPIX (HH*WW)     // 16384
#define NTAP 24
#define PAD 4
#define PW 136
#define PH 136
#define PPLANE (PW*PH)   // 18496
#define PWQ (PW/4)       // 34
#define AGR 4            // affinity channel groups per block
#define ACH (CC/AGR)     // 16 channels per thread
#define TS 16            // prop2 output tile side
#define MS 24            // intermediate tile side (TS + 2*PAD)

typedef _Float16 h2 __attribute__((ext_vector_type(2)));
typedef _Float16 h4 __attribute__((ext_vector_type(4)));
typedef _Float16 h8 __attribute__((ext_vector_type(8)));

// Tap offsets in the padded plane (row stride PW, pixel units), reference order.
constexpr int TAPOFF[NTAP] = {
    -PW-1, -PW, -PW+1, -1, 1, PW-1, PW, PW+1,
    -2*PW-2, -2*PW, -2*PW+2, -2, 2, 2*PW-2, 2*PW, 2*PW+2,
    -4*PW-4, -4*PW, -4*PW+4, -4, 4, 4*PW-4, 4*PW, 4*PW+4
};
// Same taps with row stride MS (for the LDS mid tile).
constexpr int MIDOFF[NTAP] = {
    -MS-1, -MS, -MS+1, -1, 1, MS-1, MS, MS+1,
    -2*MS-2, -2*MS, -2*MS+2, -2, 2, 2*MS-2, 2*MS, 2*MS+2,
    -4*MS-4, -4*MS, -4*MS+4, -4, 4, 4*MS-4, 4*MS, 4*MS+4
};
// Affinity pair-kernel: row index (0..6 <-> dy {-4,-2,-1,0,1,2,4}) and px0 col
// (rb column units, 0 == w0-4) per tap, reference order.
constexpr int RDY[7] = {-4, -2, -1, 0, 1, 2, 4};
constexpr int KR[NTAP] = {2,2,2,3,3,4,4,4, 1,1,1,3,3,5,5,5, 0,0,0,3,3,6,6,6};
constexpr int KC[NTAP] = {3,4,5,3,5,3,4,5, 2,4,6,2,6,2,4,6, 0,4,8,0,8,0,4,8};

__device__ __forceinline__ int clampi(int v, int lo, int hi) {
    return v < lo ? lo : (v > hi ? hi : v);
}

// ---- pad feats: edge-replicate [B,C,128,128] f32 -> [B,C,136,136] fp16 -----
__global__ __launch_bounds__(256) void pad_feats_kernel(
    const float* __restrict__ feats, _Float16* __restrict__ pfeats) {
    int t = blockIdx.x * blockDim.x + threadIdx.x;
    const int total = BB * CC * PH * PWQ;
    if (t >= total) return;
    int q = t % PWQ;
    int rest = t / PWQ;
    int ph = rest % PH;
    int pl = rest / PH;
    const float* sp = feats + (size_t)pl * NPIX + (size_t)clampi(ph - PAD, 0, HH - 1) * WW;
    h4 v;
    v[0] = (_Float16)sp[clampi(q * 4 + 0 - PAD, 0, WW - 1)];
    v[1] = (_Float16)sp[clampi(q * 4 + 1 - PAD, 0, WW - 1)];
    v[2] = (_Float16)sp[clampi(q * 4 + 2 - PAD, 0, WW - 1)];
    v[3] = (_Float16)sp[clampi(q * 4 + 3 - PAD, 0, WW - 1)];
    *((h4*)(pfeats + (size_t)pl * PPLANE + (size_t)ph * PW + q * 4)) = v;
}

// ---- fused affinity + mask-pack: block = one image row (128 px) of one b ---
// thread = 2 px x 16 ch (4 channel groups).  Also writes the channel-last
// padded mask (pm) for this row, replacing the pad_mask dispatch.
// aff layout: [b][3][NPIX] h8 quads (8 taps each, fp16).
__global__ __launch_bounds__(256) void affinity_kernel(
    const _Float16* __restrict__ pfeats, const float* __restrict__ mask,
    h8* __restrict__ aff, _Float16* __restrict__ pm) {
    __shared__ float red[AGR][NTAP][128];   // float2 writes: conflict-free

    int t = threadIdx.x;
    int cg = t >> 6;                 // 0..3
    int pr = t & 63;                 // pair 0..63
    int w0 = pr * 2;
    int h  = blockIdx.x & 127;
    int b  = blockIdx.x >> 7;

    // ---- fold pad_mask: t<128 packs mask row h -> pm (with halo replication)
    if (t < 128) {
        int px = t;
        const float* mp = mask + (size_t)b * CHN * NPIX + (size_t)h * WW + px;
        h8 o0, o1, o2;
        #pragma unroll
        for (int c = 0; c < 8; ++c)  o0[c] = (_Float16)mp[(size_t)c * NPIX];
        #pragma unroll
        for (int c = 0; c < 8; ++c)  o1[c] = (_Float16)mp[(size_t)(c + 8) * NPIX];
        #pragma unroll
        for (int c = 0; c < 5; ++c)  o2[c] = (_Float16)mp[(size_t)(c + 16) * NPIX];
        o2[5] = (_Float16)0.f; o2[6] = (_Float16)0.f; o2[7] = (_Float16)0.f;
        _Float16* pd = pm + (size_t)b * PPLANE * CHP;
        int pp = (h + PAD) * PW + (px + PAD);
        int x0 = (px == 0) ? -PAD : 0, x1 = (px == WW - 1) ? PAD : 0;
        int y0 = (h == 0) ? -PAD : 0, y1 = (h == HH - 1) ? PAD : 0;
        for (int dy = y0; dy <= y1; ++dy)
            for (int dx = x0; dx <= x1; ++dx) {
                _Float16* dp = pd + (size_t)(pp + dy * PW + dx) * CHP;
                *((h8*)(dp + 0))  = o0;
                *((h8*)(dp + 8))  = o1;
                *((h8*)(dp + 16)) = o2;
            }
    }

    // ---- pair affinity accumulation
    const _Float16* fb = pfeats + (size_t)(b * CC + cg * ACH) * PPLANE
                       + (size_t)(h + PAD) * PW + w0;   // padded col w0 == unpadded w0-4

    float acc[48];
    #pragma unroll
    for (int k = 0; k < 48; ++k) acc[k] = 0.f;

    for (int c = 0; c < ACH; ++c) {
        const _Float16* base = fb + (size_t)c * PPLANE;
        h2 rb[7][5];
        #pragma unroll
        for (int r = 0; r < 7; ++r) {
            const h2* rp = (const h2*)(base + RDY[r] * PW);
            #pragma unroll
            for (int i = 0; i < 5; ++i) rb[r][i] = rp[i];
        }
        float q0 = (float)rb[3][2][0];
        float q1 = (float)rb[3][2][1];
        float sum0 = 3.f * q0, ss0 = 3.f * q0 * q0;
        float sum1 = 3.f * q1, ss1 = 3.f * q1 * q1;
        #pragma unroll
        for (int k = 0; k < NTAP; ++k) {
            float x0 = (float)rb[KR[k]][KC[k] >> 1][KC[k] & 1];
            float x1 = (float)rb[KR[k]][(KC[k]+1) >> 1][(KC[k]+1) & 1];
            sum0 += x0; ss0 = fmaf(x0, x0, ss0);
            sum1 += x1; ss1 = fmaf(x1, x1, ss1);
        }
        float var0 = (ss0 - sum0 * sum0 * (1.f/27.f)) * (1.f/26.f);
        float var1 = (ss1 - sum1 * sum1 * (1.f/27.f)) * (1.f/26.f);
        float inv0 = 1.f / (1e-8f + 0.1f * sqrtf(fmaxf(var0, 0.f)));
        float inv1 = 1.f / (1e-8f + 0.1f * sqrtf(fmaxf(var1, 0.f)));
        #pragma unroll
        for (int k = 0; k < NTAP; ++k) {
            float x0 = (float)rb[KR[k]][KC[k] >> 1][KC[k] & 1];
            float x1 = (float)rb[KR[k]][(KC[k]+1) >> 1][(KC[k]+1) & 1];
            acc[2*k]   = fmaf(fabsf(x0 - q0), inv0, acc[2*k]);
            acc[2*k+1] = fmaf(fabsf(x1 - q1), inv1, acc[2*k+1]);
        }
    }

    #pragma unroll
    for (int k = 0; k < NTAP; ++k)
        *((float2*)&red[cg][k][w0]) = make_float2(acc[2*k], acc[2*k+1]);
    __syncthreads();

    // ---- softmax + store (one px per thread, t<128)
    if (t < 128) {
        int px = t;
        float s[NTAP];
        #pragma unroll
        for (int k = 0; k < NTAP; ++k)
            s[k] = (red[0][k][px] + red[1][k][px]) + (red[2][k][px] + red[3][k][px]);
        float mn = s[0];
        #pragma unroll
        for (int k = 1; k < NTAP; ++k) mn = fminf(mn, s[k]);
        float e[NTAP];
        float tot = 0.f;
        #pragma unroll
        for (int k = 0; k < NTAP; ++k) {
            e[k] = __expf((mn - s[k]) * (1.f/CC));
            tot += e[k];
        }
        float ivt = 1.f / tot;
        int pix = h * WW + px;
        #pragma unroll
        for (int j = 0; j < 3; ++j) {
            h8 q;
            #pragma unroll
            for (int i = 0; i < 8; ++i) q[i] = (_Float16)(e[8*j + i] * ivt);
            aff[((size_t)b * 3 + j) * NPIX + pix] = q;
        }
    }
}

// ---- prop2: TWO fused iterations, 16x16 tile, 768 blocks (R13, unchanged) --
__global__ __launch_bounds__(256, 3) void prop2_kernel(
    const _Float16* __restrict__ src, const h8* __restrict__ aff,
    _Float16* __restrict__ dstp, float* __restrict__ dstf, int final_iter) {
    __shared__ __align__(16) _Float16 mid[MS * MS * 8];   // 9.2 KB

    int tid = threadIdx.x;
    int tx = (blockIdx.x & 7) * TS;
    int ty = (blockIdx.x >> 3) * TS;
    int cg = blockIdx.y;             // 0..2 (channels cg*8 .. cg*8+7)
    int b  = blockIdx.z;

    // ---- phase 1: intermediate iteration into LDS (2.25 px/thread)
    for (int p = tid; p < MS * MS; p += 256) {
        int y = p / MS, x = p - y * MS;
        int gh = clampi(ty + y - PAD, 0, HH - 1);
        int gw = clampi(tx + x - PAD, 0, WW - 1);
        int pix = gh * WW + gw;

        float A[NTAP];
        #pragma unroll
        for (int j = 0; j < 3; ++j) {
            h8 q = aff[((size_t)b * 3 + j) * NPIX + pix];
            #pragma unroll
            for (int i = 0; i < 8; ++i) A[8*j + i] = (float)q[i];
        }

        const _Float16* base = src
            + ((size_t)b * PPLANE + (gh + PAD) * PW + (gw + PAD)) * CHP + cg * 8;
        float acc[8];
        #pragma unroll
        for (int i = 0; i < 8; ++i) acc[i] = 0.f;
        #pragma unroll
        for (int k = 0; k < NTAP; ++k) {
            h8 m = *((const h8*)(base + (ptrdiff_t)TAPOFF[k] * CHP));
            #pragma unroll
            for (int i = 0; i < 8; ++i) acc[i] = fmaf((float)m[i], A[k], acc[i]);
        }
        h8 o;
        #pragma unroll
        for (int i = 0; i < 8; ++i) o[i] = (_Float16)acc[i];
        *((h8*)(mid + (size_t)p * 8)) = o;
    }
    __syncthreads();

    // ---- phase 2: final iteration of the pair from LDS (1 px/thread)
    {
        int p = tid;
        int y2 = p >> 4, x2 = p & 15;
        int gh = ty + y2, gw = tx + x2;
        int pix = gh * WW + gw;

        float A[NTAP];
        #pragma unroll
        for (int j = 0; j < 3; ++j) {
            h8 q = aff[((size_t)b * 3 + j) * NPIX + pix];
            #pragma unroll
            for (int i = 0; i < 8; ++i) A[8*j + i] = (float)q[i];
        }

        const _Float16* mbase = mid + ((size_t)(y2 + PAD) * MS + (x2 + PAD)) * 8;
        float acc[8];
        #pragma unroll
        for (int i = 0; i < 8; ++i) acc[i] = 0.f;
        #pragma unroll
        for (int k = 0; k < NTAP; ++k) {
            h8 m = *((const h8*)(mbase + (ptrdiff_t)MIDOFF[k] * 8));
            #pragma unroll
            for (int i = 0; i < 8; ++i) acc[i] = fmaf((float)m[i], A[k], acc[i]);
        }

        if (final_iter) {
            float* ob = dstf + (size_t)b * CHN * NPIX + pix;
            #pragma unroll
            for (int i = 0; i < 8; ++i) {
                int ch = cg * 8 + i;
                if (ch < CHN) ob[(size_t)ch * NPIX] = acc[i];
            }
        } else {
            h8 o;
            #pragma unroll
            for (int i = 0; i < 8; ++i) o[i] = (_Float16)acc[i];
            _Float16* pd = dstp + (size_t)b * PPLANE * CHP + cg * 8;
            int pp = (gh + PAD) * PW + (gw + PAD);
            int x0 = (gw == 0) ? -PAD : 0, x1 = (gw == WW - 1) ? PAD : 0;
            int y0 = (gh == 0) ? -PAD : 0, y1 = (gh == HH - 1) ? PAD : 0;
            for (int dy = y0; dy <= y1; ++dy)
                for (int dx = x0; dx <= x1; ++dx)
                    *((h8*)(pd + (size_t)(pp + dy * PW + dx) * CHP)) = o;
        }
    }
}

extern "C" void kernel_launch(void* const* d_in, const int* in_sizes, int n_in,
                              void* d_out, int out_size, void* d_ws, size_t ws_size,
                              hipStream_t stream) {
    const float* feats = (const float*)d_in[0];
    const float* mask  = (const float*)d_in[1];
    float* out = (float*)d_out;

    const size_t pfeatsE = (size_t)BB * CC * PPLANE;    // halfs
    const size_t affQ    = (size_t)BB * 3 * NPIX;       // h8 (16 B each)
    const size_t pmE     = (size_t)BB * PPLANE * CHP;   // halfs

    _Float16* pfeats = (_Float16*)d_ws;
    h8*       aff    = (h8*)(pfeats + pfeatsE);
    _Float16* pm0    = (_Float16*)((char*)aff + affQ * sizeof(h8));
    _Float16* pm1    = pm0 + pmE;

    {
        int total = BB * CC * PH * PWQ;
        pad_feats_kernel<<<dim3((total + 255) / 256), dim3(256), 0, stream>>>(feats, pfeats);
    }
    // affinity also packs mask -> pm0 (pad_mask folded in)
    affinity_kernel<<<dim3(BB * HH), dim3(256), 0, stream>>>(pfeats, mask, aff, pm0);

    // 5 fused dispatches = 10 iterations; ping-pong pm0/pm1, last writes f32 out
    dim3 g2(64, 3, BB);
    prop2_kernel<<<g2, dim3(256), 0, stream>>>(pm0, aff, pm1, nullptr, 0);
    prop2_kernel<<<g2, dim3(256), 0, stream>>>(pm1, aff, pm0, nullptr, 0);
    prop2_kernel<<<g2, dim3(256), 0, stream>>>(pm0, aff, pm1, nullptr, 0);
    prop2_kernel<<<g2, dim3(256), 0, stream>>>(pm1, aff, pm0, nullptr, 0);
    prop2_kernel<<<g2, dim3(256), 0, stream>>>(pm0, aff, nullptr, out, 1);
}